// Round 9
// baseline (158.275 us; speedup 1.0000x reference)
//
#include <hip/hip_runtime.h>
#include <stdint.h>
#include <stddef.h>

// ---------------- problem constants ----------------
// B=2048, F0=39, D=16, layers 128/128/128, xk halves to 64 after each layer.
// Factored form: y_h[s,d] = sum_k W[h,k,s]*xk[b,k,d] (MFMA: A=W static, B=xk
// h-invariant -> register-cached per layer); z[b,s,d] = sum_h x0[b,h,d]*y_h[s,d]
// (4 fmac per (b,h), x0 in full f32).
// R9 = R8 with __launch_bounds__(512,2): R8's (512,4) made the compiler cap
// VGPRs at 64 (it treats the arg as 4 co-resident 512-thread blocks ->
// 2048/32waves = 64) -> h-loop spilled to scratch (WRITE_SIZE 13.4 MB vs 2 MB
// output, +5.6 MB FETCH). (512,2) -> cap 128, no spill, HW still fits
// 2 blocks/CU (4 waves/SIMD x ~112 VGPR = 448 <= 512/SIMD pool).
#define F0N  39
#define SN   128
#define NB   4             // batches per block
#define X0TS 44            // f32 stride of X0T row (b,d): 39+pad, 16B-aligned
#define XKTS 72            // u16 stride of XKT row (b,d): 64+8 pad, 16B-aligned
#define WBLK 8192          // u16 per (L,h) W block: 8 s-tiles x 2 chunks x 512
#define NHB  117           // 3*39 prepass blocks

typedef __attribute__((ext_vector_type(8))) short short8;   // MFMA A/B operand
typedef __attribute__((ext_vector_type(4))) float floatx4;  // MFMA accumulator

__device__ __forceinline__ uint16_t f2bf(float f) {         // RNE f32->bf16
  uint32_t u = __float_as_uint(f);
  u += 0x7fffu + ((u >> 16) & 1u);
  return (uint16_t)(u >> 16);
}

// ---------------- pre-pass: W fp32 -> bf16 A-fragment blocks (R6/R7-verified) ----------------
// One block per (L,h). Block layout (u16 idx in 8192):
//   (st*2+ch)*512 + lane*8 + j  where value = W[h][k=ch*32+quad*8+j][s=st*16+l16]
__global__ __launch_bounds__(256) void cin_prepass(
    const float* __restrict__ w0, const float* __restrict__ w1,
    const float* __restrict__ w2, uint16_t* __restrict__ wt) {
  __shared__ float T[64 * 132];               // [k][s], +4 pad floats per row
  const int bc = blockIdx.x;                  // 0..116
  const int L = bc / F0N;
  const int h = bc - L * F0N;
  const float* W = (L == 0) ? w0 : ((L == 1) ? w1 : w2);
  const int fk = (L == 0) ? 39 : 64;
  const int tid = threadIdx.x;

  for (int e = tid; e < 8192; e += 256) {     // coalesced fp32 read, k padded to 64
    int k = e >> 7, s = e & 127;
    T[k * 132 + s] = (k < fk) ? W[(h * fk + k) * SN + s] : 0.0f;
  }
  __syncthreads();
  uint32_t* dst = (uint32_t*)(wt + (size_t)bc * WBLK);
  for (int i = tid; i < 4096; i += 256) {     // coalesced u32 writes, frag order
    int frag = i >> 8, w = i & 255;
    int st = frag >> 1, ch = frag & 1;
    int ln = w >> 2, jp = w & 3;
    int quad = ln >> 4, l16 = ln & 15;
    int k0 = ch * 32 + quad * 8 + jp * 2;
    int s = st * 16 + l16;
    dst[i] = (uint32_t)f2bf(T[k0 * 132 + s]) | ((uint32_t)f2bf(T[(k0 + 1) * 132 + s]) << 16);
  }
}

// ---------------- fused main kernel ----------------
// 512 blocks x 512 threads (8 waves), 2 blocks/CU, 4 waves/SIMD. Block owns
// NB=4 batches; wave st owns s-tile [st*16, st*16+16) x all 4 b. Per layer:
// Bf (xk B-frags) register-cached; per h: 2 coalesced global W-frag loads
// (dist-1 register prefetch, no barriers in h-loop), float4 x0 reads per 4 h,
// 8 MFMA + 16 fmac. h runs to 40; h=39 has xs=0 (X0T pad) so its (arbitrary
// but finite) W contributes 0; its prefetch seeds the next layer's h0.
// D-layout: D[s=st*16+quad*4+r][d=l16]; sum_d = shfl_xor over l16 bits.
__global__ __launch_bounds__(512, 2) void cin_main(
    const float* __restrict__ x,       // (2048, 39, 16) fp32
    const float* __restrict__ bias0, const float* __restrict__ bias1,
    const float* __restrict__ bias2,
    const uint16_t* __restrict__ wt,   // A-frag bf16 weights (d_ws)
    float* __restrict__ out) {         // (2048, 256) fp32

  __shared__ __align__(16) float    X0T[NB * 16 * X0TS];  // x0[b][d][h] f32, 11264 B
  __shared__ __align__(16) uint16_t XKT[NB * 16 * XKTS];  // xk[b][d][k] bf16, 9216 B

  const int tid  = threadIdx.x;
  const int lane = tid & 63;
  const int st   = tid >> 6;           // wave index = s-tile
  const int l16  = lane & 15;          // = d (output col)
  const int quad = lane >> 4;
  const int bbase = blockIdx.x * NB;

  // zero X0T (h-pad 39..43 must be 0 -> xs=0 at h=39) and XKT (k-pad for L0)
  {
    float* p = X0T;                    // 2816 floats
#pragma unroll
    for (int i = 0; i < 6; i++) { int e = tid + 512 * i; if (e < 2816) p[e] = 0.f; }
    uint32_t* q = (uint32_t*)XKT;      // 2304 dwords
#pragma unroll
    for (int i = 0; i < 5; i++) { int e = tid + 512 * i; if (e < 2304) q[e] = 0u; }
  }
  __syncthreads();

  // fill X0T[b][d][h] = x[bbase+b][h][d]  (coalesced read, LDS transpose-scatter)
#pragma unroll
  for (int it = 0; it < 5; ++it) {
    int e = tid + it * 512;            // e = (b*39 + h)*16 + d, total 2496
    if (e < NB * F0N * 16) {
      float v = x[(size_t)bbase * (F0N * 16) + e];
      int d = e & 15, p = e >> 4;
      int b = p / F0N, h = p - b * F0N;
      X0T[(b * 16 + d) * X0TS + h] = v;
    }
  }
  __syncthreads();

  // build layer-0 XKT[b][d][k] = bf16(x0[b][k][d]) for k<39, 0 for k in [39,64)
  if (tid < 256) {
    int b = tid >> 6, d = (tid >> 2) & 15, kg = tid & 3;
    const float* src = &X0T[(b * 16 + d) * X0TS];
    uint32_t* drow = (uint32_t*)&XKT[(b * 16 + d) * XKTS + kg * 16];
#pragma unroll
    for (int i2 = 0; i2 < 8; i2++) {
      int k0 = kg * 16 + i2 * 2;
      uint32_t lo = (k0 < 39)     ? (uint32_t)f2bf(src[k0])     : 0u;
      uint32_t hi = (k0 + 1 < 39) ? (uint32_t)f2bf(src[k0 + 1]) : 0u;
      drow[i2] = lo | (hi << 16);
    }
  }
  __syncthreads();   // XKT build visible for Bf loads

  // per-wave global W base (u16 units)
  const uint16_t* wlane = wt + st * 1024 + (size_t)lane * 8;

  // seed prefetch: (L0, h0)
  short8 Wc0 = *(const short8*)(wlane);
  short8 Wc1 = *(const short8*)(wlane + 512);

#pragma unroll 1
  for (int L = 0; L < 3; ++L) {
    // register-cache B-fragments (h-invariant within layer)
    short8 Bf0[NB], Bf1[NB];
#pragma unroll
    for (int b = 0; b < NB; ++b) {
      const uint16_t* r = XKT + (b * 16 + l16) * XKTS + quad * 8;
      Bf0[b] = *(const short8*)r;          // k 0..31 chunk
      Bf1[b] = *(const short8*)(r + 32);   // k 32..63 chunk
    }
    const float* bp = (L == 0) ? bias0 : ((L == 1) ? bias1 : bias2);
    float bvr[4];
#pragma unroll
    for (int r = 0; r < 4; ++r) bvr[r] = bp[st * 16 + quad * 4 + r];

    floatx4 z[NB] = {};
    const floatx4 zero4 = {0.f, 0.f, 0.f, 0.f};

#pragma unroll 1
    for (int h4 = 0; h4 < 10; ++h4) {
      float4 xv[NB];                   // x0 for h = h4*4 .. h4*4+3 (h>=39 -> 0 pad)
#pragma unroll
      for (int b = 0; b < NB; ++b)
        xv[b] = *(const float4*)&X0T[(b * 16 + l16) * X0TS + h4 * 4];

#pragma unroll
      for (int hi = 0; hi < 4; ++hi) {
        const int h = h4 * 4 + hi;
        // distance-1 prefetch of next h (or next layer's h0); wave-uniform addr
        short8 Wn0, Wn1;
        {
          int Ln = L, hh = h + 1;
          if (hh >= 39) { if (L < 2) { Ln = L + 1; hh = 0; } else hh = 38; }
          const uint16_t* wl = wlane + (size_t)(Ln * F0N + hh) * WBLK;
          Wn0 = *(const short8*)wl;
          Wn1 = *(const short8*)(wl + 512);
        }

#pragma unroll
        for (int b = 0; b < NB; ++b) {
          floatx4 y = __builtin_amdgcn_mfma_f32_16x16x32_bf16(Wc0, Bf0[b], zero4, 0, 0, 0);
          y = __builtin_amdgcn_mfma_f32_16x16x32_bf16(Wc1, Bf1[b], y, 0, 0, 0);
          const float xs = (hi == 0) ? xv[b].x : (hi == 1) ? xv[b].y
                         : (hi == 2) ? xv[b].z : xv[b].w;
#pragma unroll
          for (int r = 0; r < 4; ++r) z[b][r] += xs * y[r];
        }
        Wc0 = Wn0;
        Wc1 = Wn1;
      }
    }

    // ---- epilogue: bias+relu; xk handoff; sum_d (over l16) -> out ----
#pragma unroll
    for (int b = 0; b < NB; ++b) {
#pragma unroll
      for (int r = 0; r < 4; ++r) {
        float t = fmaxf(z[b][r] + bvr[r], 0.f);
        if (L < 2 && st < 4)               // xk = relu(z)[:, :64]; k = s < 64
          XKT[(b * 16 + l16) * XKTS + st * 16 + quad * 4 + r] = f2bf(t);
        float s4 = t;                       // reduce over d = l16 (bits 0..3)
        s4 += __shfl_xor(s4, 1);
        s4 += __shfl_xor(s4, 2);
        s4 += __shfl_xor(s4, 4);
        s4 += __shfl_xor(s4, 8);
        if (l16 == 0) {
          int s = st * 16 + quad * 4 + r;
          // concat: L0 s64:128 -> 0:64 ; L1 s64:128 -> 64:128 ; L2 s -> 128:256
          if (L == 2)       out[(size_t)(bbase + b) * 256 + 128 + s] = s4;
          else if (s >= 64) out[(size_t)(bbase + b) * 256 + L * 64 + (s - 64)] = s4;
        }
      }
    }
    if (L < 2) __syncthreads();   // handoff writes visible before next-layer Bf loads
  }
}

extern "C" void kernel_launch(void* const* d_in, const int* in_sizes, int n_in,
                              void* d_out, int out_size, void* d_ws, size_t ws_size,
                              hipStream_t stream) {
  (void)in_sizes; (void)n_in; (void)out_size; (void)ws_size;
  const float* x  = (const float*)d_in[0];
  const float* w0 = (const float*)d_in[1];
  const float* b0 = (const float*)d_in[2];
  const float* w1 = (const float*)d_in[3];
  const float* b1 = (const float*)d_in[4];
  const float* w2 = (const float*)d_in[5];
  const float* b2 = (const float*)d_in[6];
  uint16_t* wt    = (uint16_t*)d_ws;   // 117 * 8192 * 2 = 1,916,928 B

  cin_prepass<<<NHB, 256, 0, stream>>>(w0, w1, w2, wt);
  cin_main<<<512, 512, 0, stream>>>(x, b0, b1, b2, wt, (float*)d_out);
}

// Round 10
// 158.043 us; speedup vs baseline: 1.0015x; 1.0015x over previous
//
#include <hip/hip_runtime.h>
#include <stdint.h>
#include <stddef.h>

// ---------------- problem constants ----------------
// B=2048, F0=39, D=16, layers 128/128/128, xk halves to 64 after each layer.
// Factored form: y_h[s,d] = sum_k W[h,k,s]*xk[b,k,d] (MFMA: A=W static, B=xk
// h-invariant -> register-cached per layer); z[b,s,d] = sum_h x0[b,h,d]*y_h[s,d]
// (4 fmac per (b,h), x0 in full f32).
// R10 = R9 with PLAIN __launch_bounds__(512): the 2-arg form acts as an exact
// waves-per-EU pin on this toolchain — (512,4) pinned 4 waves/EU but capped
// VGPR at 64 (spill, R8); (512,2) gave 128-reg budget but pinned 2 waves/EU
// = 1 block/CU (R9, occ 21% == R7's 1-block grid). Plain bounds -> natural
// ~104 regs/wave (R9 proved no spill) -> descriptor allows 4 waves/SIMD ->
// HW places 2 blocks/CU with no spill.
#define F0N  39
#define SN   128
#define NB   4             // batches per block
#define X0TS 44            // f32 stride of X0T row (b,d): 39+pad, 16B-aligned
#define XKTS 72            // u16 stride of XKT row (b,d): 64+8 pad, 16B-aligned
#define WBLK 8192          // u16 per (L,h) W block: 8 s-tiles x 2 chunks x 512
#define NHB  117           // 3*39 prepass blocks

typedef __attribute__((ext_vector_type(8))) short short8;   // MFMA A/B operand
typedef __attribute__((ext_vector_type(4))) float floatx4;  // MFMA accumulator

__device__ __forceinline__ uint16_t f2bf(float f) {         // RNE f32->bf16
  uint32_t u = __float_as_uint(f);
  u += 0x7fffu + ((u >> 16) & 1u);
  return (uint16_t)(u >> 16);
}

// ---------------- pre-pass: W fp32 -> bf16 A-fragment blocks (R6/R7-verified) ----------------
// One block per (L,h). Block layout (u16 idx in 8192):
//   (st*2+ch)*512 + lane*8 + j  where value = W[h][k=ch*32+quad*8+j][s=st*16+l16]
__global__ __launch_bounds__(256) void cin_prepass(
    const float* __restrict__ w0, const float* __restrict__ w1,
    const float* __restrict__ w2, uint16_t* __restrict__ wt) {
  __shared__ float T[64 * 132];               // [k][s], +4 pad floats per row
  const int bc = blockIdx.x;                  // 0..116
  const int L = bc / F0N;
  const int h = bc - L * F0N;
  const float* W = (L == 0) ? w0 : ((L == 1) ? w1 : w2);
  const int fk = (L == 0) ? 39 : 64;
  const int tid = threadIdx.x;

  for (int e = tid; e < 8192; e += 256) {     // coalesced fp32 read, k padded to 64
    int k = e >> 7, s = e & 127;
    T[k * 132 + s] = (k < fk) ? W[(h * fk + k) * SN + s] : 0.0f;
  }
  __syncthreads();
  uint32_t* dst = (uint32_t*)(wt + (size_t)bc * WBLK);
  for (int i = tid; i < 4096; i += 256) {     // coalesced u32 writes, frag order
    int frag = i >> 8, w = i & 255;
    int st = frag >> 1, ch = frag & 1;
    int ln = w >> 2, jp = w & 3;
    int quad = ln >> 4, l16 = ln & 15;
    int k0 = ch * 32 + quad * 8 + jp * 2;
    int s = st * 16 + l16;
    dst[i] = (uint32_t)f2bf(T[k0 * 132 + s]) | ((uint32_t)f2bf(T[(k0 + 1) * 132 + s]) << 16);
  }
}

// ---------------- fused main kernel ----------------
// 512 blocks x 512 threads (8 waves), target 2 blocks/CU, 4 waves/SIMD.
// Block owns NB=4 batches; wave st owns s-tile [st*16, st*16+16) x all 4 b.
// Per layer: Bf (xk B-frags) register-cached; per h: 2 coalesced global
// W-frag loads (dist-1 register prefetch, no barriers in h-loop), float4 x0
// reads per 4 h, 8 MFMA + 16 fmac. h runs to 40; h=39 has xs=0 (X0T pad) so
// its W contributes 0; its prefetch seeds the next layer's h0.
// D-layout: D[s=st*16+quad*4+r][d=l16]; sum_d = shfl_xor over l16 bits.
__global__ __launch_bounds__(512) void cin_main(
    const float* __restrict__ x,       // (2048, 39, 16) fp32
    const float* __restrict__ bias0, const float* __restrict__ bias1,
    const float* __restrict__ bias2,
    const uint16_t* __restrict__ wt,   // A-frag bf16 weights (d_ws)
    float* __restrict__ out) {         // (2048, 256) fp32

  __shared__ __align__(16) float    X0T[NB * 16 * X0TS];  // x0[b][d][h] f32, 11264 B
  __shared__ __align__(16) uint16_t XKT[NB * 16 * XKTS];  // xk[b][d][k] bf16, 9216 B

  const int tid  = threadIdx.x;
  const int lane = tid & 63;
  const int st   = tid >> 6;           // wave index = s-tile
  const int l16  = lane & 15;          // = d (output col)
  const int quad = lane >> 4;
  const int bbase = blockIdx.x * NB;

  // zero X0T (h-pad 39..43 must be 0 -> xs=0 at h=39) and XKT (k-pad for L0)
  {
    float* p = X0T;                    // 2816 floats
#pragma unroll
    for (int i = 0; i < 6; i++) { int e = tid + 512 * i; if (e < 2816) p[e] = 0.f; }
    uint32_t* q = (uint32_t*)XKT;      // 2304 dwords
#pragma unroll
    for (int i = 0; i < 5; i++) { int e = tid + 512 * i; if (e < 2304) q[e] = 0u; }
  }
  __syncthreads();

  // fill X0T[b][d][h] = x[bbase+b][h][d]  (coalesced read, LDS transpose-scatter)
#pragma unroll
  for (int it = 0; it < 5; ++it) {
    int e = tid + it * 512;            // e = (b*39 + h)*16 + d, total 2496
    if (e < NB * F0N * 16) {
      float v = x[(size_t)bbase * (F0N * 16) + e];
      int d = e & 15, p = e >> 4;
      int b = p / F0N, h = p - b * F0N;
      X0T[(b * 16 + d) * X0TS + h] = v;
    }
  }
  __syncthreads();

  // build layer-0 XKT[b][d][k] = bf16(x0[b][k][d]) for k<39, 0 for k in [39,64)
  if (tid < 256) {
    int b = tid >> 6, d = (tid >> 2) & 15, kg = tid & 3;
    const float* src = &X0T[(b * 16 + d) * X0TS];
    uint32_t* drow = (uint32_t*)&XKT[(b * 16 + d) * XKTS + kg * 16];
#pragma unroll
    for (int i2 = 0; i2 < 8; i2++) {
      int k0 = kg * 16 + i2 * 2;
      uint32_t lo = (k0 < 39)     ? (uint32_t)f2bf(src[k0])     : 0u;
      uint32_t hi = (k0 + 1 < 39) ? (uint32_t)f2bf(src[k0 + 1]) : 0u;
      drow[i2] = lo | (hi << 16);
    }
  }
  __syncthreads();   // XKT build visible for Bf loads

  // per-wave global W base (u16 units)
  const uint16_t* wlane = wt + st * 1024 + (size_t)lane * 8;

  // seed prefetch: (L0, h0)
  short8 Wc0 = *(const short8*)(wlane);
  short8 Wc1 = *(const short8*)(wlane + 512);

#pragma unroll 1
  for (int L = 0; L < 3; ++L) {
    // register-cache B-fragments (h-invariant within layer)
    short8 Bf0[NB], Bf1[NB];
#pragma unroll
    for (int b = 0; b < NB; ++b) {
      const uint16_t* r = XKT + (b * 16 + l16) * XKTS + quad * 8;
      Bf0[b] = *(const short8*)r;          // k 0..31 chunk
      Bf1[b] = *(const short8*)(r + 32);   // k 32..63 chunk
    }
    const float* bp = (L == 0) ? bias0 : ((L == 1) ? bias1 : bias2);
    float bvr[4];
#pragma unroll
    for (int r = 0; r < 4; ++r) bvr[r] = bp[st * 16 + quad * 4 + r];

    floatx4 z[NB] = {};
    const floatx4 zero4 = {0.f, 0.f, 0.f, 0.f};

#pragma unroll 1
    for (int h4 = 0; h4 < 10; ++h4) {
      float4 xv[NB];                   // x0 for h = h4*4 .. h4*4+3 (h>=39 -> 0 pad)
#pragma unroll
      for (int b = 0; b < NB; ++b)
        xv[b] = *(const float4*)&X0T[(b * 16 + l16) * X0TS + h4 * 4];

#pragma unroll
      for (int hi = 0; hi < 4; ++hi) {
        const int h = h4 * 4 + hi;
        // distance-1 prefetch of next h (or next layer's h0); wave-uniform addr
        short8 Wn0, Wn1;
        {
          int Ln = L, hh = h + 1;
          if (hh >= 39) { if (L < 2) { Ln = L + 1; hh = 0; } else hh = 38; }
          const uint16_t* wl = wlane + (size_t)(Ln * F0N + hh) * WBLK;
          Wn0 = *(const short8*)wl;
          Wn1 = *(const short8*)(wl + 512);
        }

#pragma unroll
        for (int b = 0; b < NB; ++b) {
          floatx4 y = __builtin_amdgcn_mfma_f32_16x16x32_bf16(Wc0, Bf0[b], zero4, 0, 0, 0);
          y = __builtin_amdgcn_mfma_f32_16x16x32_bf16(Wc1, Bf1[b], y, 0, 0, 0);
          const float xs = (hi == 0) ? xv[b].x : (hi == 1) ? xv[b].y
                         : (hi == 2) ? xv[b].z : xv[b].w;
#pragma unroll
          for (int r = 0; r < 4; ++r) z[b][r] += xs * y[r];
        }
        Wc0 = Wn0;
        Wc1 = Wn1;
      }
    }

    // ---- epilogue: bias+relu; xk handoff; sum_d (over l16) -> out ----
#pragma unroll
    for (int b = 0; b < NB; ++b) {
#pragma unroll
      for (int r = 0; r < 4; ++r) {
        float t = fmaxf(z[b][r] + bvr[r], 0.f);
        if (L < 2 && st < 4)               // xk = relu(z)[:, :64]; k = s < 64
          XKT[(b * 16 + l16) * XKTS + st * 16 + quad * 4 + r] = f2bf(t);
        float s4 = t;                       // reduce over d = l16 (bits 0..3)
        s4 += __shfl_xor(s4, 1);
        s4 += __shfl_xor(s4, 2);
        s4 += __shfl_xor(s4, 4);
        s4 += __shfl_xor(s4, 8);
        if (l16 == 0) {
          int s = st * 16 + quad * 4 + r;
          // concat: L0 s64:128 -> 0:64 ; L1 s64:128 -> 64:128 ; L2 s -> 128:256
          if (L == 2)       out[(size_t)(bbase + b) * 256 + 128 + s] = s4;
          else if (s >= 64) out[(size_t)(bbase + b) * 256 + L * 64 + (s - 64)] = s4;
        }
      }
    }
    if (L < 2) __syncthreads();   // handoff writes visible before next-layer Bf loads
  }
}

extern "C" void kernel_launch(void* const* d_in, const int* in_sizes, int n_in,
                              void* d_out, int out_size, void* d_ws, size_t ws_size,
                              hipStream_t stream) {
  (void)in_sizes; (void)n_in; (void)out_size; (void)ws_size;
  const float* x  = (const float*)d_in[0];
  const float* w0 = (const float*)d_in[1];
  const float* b0 = (const float*)d_in[2];
  const float* w1 = (const float*)d_in[3];
  const float* b1 = (const float*)d_in[4];
  const float* w2 = (const float*)d_in[5];
  const float* b2 = (const float*)d_in[6];
  uint16_t* wt    = (uint16_t*)d_ws;   // 117 * 8192 * 2 = 1,916,928 B

  cin_prepass<<<NHB, 256, 0, stream>>>(w0, w1, w2, wt);
  cin_main<<<512, 512, 0, stream>>>(x, b0, b1, b2, wt, (float*)d_out);
}

// Round 11
// 135.411 us; speedup vs baseline: 1.1688x; 1.1671x over previous
//
#include <hip/hip_runtime.h>
#include <stdint.h>
#include <stddef.h>

// ---------------- problem constants ----------------
// B=2048, F0=39, D=16, layers 128/128/128, xk halves to 64 after each layer.
// Factored form: y_h[s,d] = sum_k W[h,k,s]*xk[b,k,d] (MFMA: A=W static, B=xk
// h-invariant -> register-cached per layer); z[b,s,d] = sum_h x0[b,h,d]*y_h[s,d].
// R11: 256 blocks x 1024 threads (16 waves) -> 4 waves/SIMD with ONE block/CU
// (R7-R10 proved this block-shape-limited: 512-thread blocks at VGPR>64 only
// ever got 2 waves/SIMD; the (512,4)/(512,2)/plain launch-bounds ladder
// couldn't give both no-spill and 2 blocks/CU). Wave = (st in [0,8), bg in
// [0,2)): 4 batches x 16 s each; bg-pair waves read identical W lines (L1 hit,
// GPU-wide L2 W traffic halves). Scalar x0 ds_reads save 12 VGPRs.
#define F0N  39
#define SN   128
#define NB   8             // batches per block
#define X0TS 44            // f32 stride of X0T row (b,d): 39+pad, 16B-aligned
#define XKTS 72            // u16 stride of XKT row (b,d): 64+8 pad, 16B-aligned
#define WBLK 8192          // u16 per (L,h) W block: 8 s-tiles x 2 chunks x 512
#define NHB2 234           // 3*39*2 prepass blocks (one per (L,h,k-half))

typedef __attribute__((ext_vector_type(8))) short short8;   // MFMA A/B operand
typedef __attribute__((ext_vector_type(4))) float floatx4;  // MFMA accumulator

__device__ __forceinline__ uint16_t f2bf(float f) {         // RNE f32->bf16
  uint32_t u = __float_as_uint(f);
  u += 0x7fffu + ((u >> 16) & 1u);
  return (uint16_t)(u >> 16);
}

// ---------------- pre-pass: W fp32 -> bf16 A-fragment blocks ----------------
// One block per (L,h,ch). Output layout identical to R6-R10 (verified):
//   wt[(L*39+h)*WBLK + (st*2+ch)*512 + lane*8 + j],
//   value = W[h][k=ch*32+quad*8+j][s=st*16+l16].
__global__ __launch_bounds__(256) void cin_prepass(
    const float* __restrict__ w0, const float* __restrict__ w1,
    const float* __restrict__ w2, uint16_t* __restrict__ wt) {
  __shared__ float T[32 * 132];               // [k_local][s], +4 pad floats/row
  const int bc = blockIdx.x;                  // 0..233
  const int ch = bc & 1;
  const int lh = bc >> 1;                     // 0..116
  const int L = lh / F0N;
  const int h = lh - L * F0N;
  const float* W = (L == 0) ? w0 : ((L == 1) ? w1 : w2);
  const int fk = (L == 0) ? 39 : 64;
  const int tid = threadIdx.x;

  for (int e = tid; e < 4096; e += 256) {     // coalesced fp32 read
    int kc = e >> 7, s = e & 127;
    int k = ch * 32 + kc;
    T[kc * 132 + s] = (k < fk) ? W[(h * fk + k) * SN + s] : 0.0f;
  }
  __syncthreads();
  uint32_t* dst = (uint32_t*)(wt + (size_t)lh * WBLK);
  for (int i = tid; i < 2048; i += 256) {     // coalesced u32 writes, frag order
    int st = i >> 8, w = i & 255;
    int ln = w >> 2, jp = w & 3;
    int quad = ln >> 4, l16 = ln & 15;
    int k0 = quad * 8 + jp * 2;               // local k within this half
    int s = st * 16 + l16;
    dst[(size_t)(st * 2 + ch) * 256 + w] =
        (uint32_t)f2bf(T[k0 * 132 + s]) | ((uint32_t)f2bf(T[(k0 + 1) * 132 + s]) << 16);
  }
}

// ---------------- fused main kernel ----------------
// 256 blocks x 1024 threads (16 waves), 1 block/CU, 4 waves/SIMD.
// Block owns NB=8 batches x full s (xk handoff block-local). Wave (st,bg):
// s-tile [st*16,st*16+16) x batches [bg*4, bg*4+4). Per layer: Bf register-
// cached; per h: 2 coalesced global W-frag loads (dist-1 register prefetch,
// no barriers in h-loop), 4 scalar x0 ds_reads, 8 MFMA + 16 fmac. h runs to
// 40; h=39 has xs=0 (X0T pad) so its W contributes 0; its prefetch seeds the
// next layer's h0. D-layout: D[s=st*16+quad*4+r][d=l16]; sum_d over l16 bits.
__global__ __launch_bounds__(1024) void cin_main(
    const float* __restrict__ x,       // (2048, 39, 16) fp32
    const float* __restrict__ bias0, const float* __restrict__ bias1,
    const float* __restrict__ bias2,
    const uint16_t* __restrict__ wt,   // A-frag bf16 weights (d_ws)
    float* __restrict__ out) {         // (2048, 256) fp32

  __shared__ __align__(16) float    X0T[NB * 16 * X0TS];  // x0[b][d][h] f32, 22528 B
  __shared__ __align__(16) uint16_t XKT[NB * 16 * XKTS];  // xk[b][d][k] bf16, 18432 B

  const int tid  = threadIdx.x;
  const int lane = tid & 63;
  const int wave = tid >> 6;           // 0..15
  const int st   = wave >> 1;          // s-tile 0..7
  const int bg   = wave & 1;           // batch group 0..1
  const int l16  = lane & 15;          // = d (output col)
  const int quad = lane >> 4;
  const int bbase = blockIdx.x * NB;

  // zero X0T (h-pad 39..43 must be 0 -> xs=0 at h=39) and XKT (k-pad for L0)
  {
    float* p = X0T;                    // 5632 floats
#pragma unroll
    for (int i = 0; i < 6; i++) { int e = tid + 1024 * i; if (e < 5632) p[e] = 0.f; }
    uint32_t* q = (uint32_t*)XKT;      // 4608 dwords
#pragma unroll
    for (int i = 0; i < 5; i++) { int e = tid + 1024 * i; if (e < 4608) q[e] = 0u; }
  }
  __syncthreads();

  // fill X0T[b][d][h] = x[bbase+b][h][d]  (coalesced read, LDS transpose-scatter)
#pragma unroll
  for (int it = 0; it < 5; ++it) {
    int e = tid + it * 1024;           // e = (b*39 + h)*16 + d, total 4992
    if (e < NB * F0N * 16) {
      float v = x[(size_t)bbase * (F0N * 16) + e];
      int d = e & 15, p = e >> 4;
      int b = p / F0N, h = p - b * F0N;
      X0T[(b * 16 + d) * X0TS + h] = v;
    }
  }
  __syncthreads();

  // build layer-0 XKT[b][d][k] = bf16(x0[b][k][d]) for k<39, 0 for k in [39,64)
  if (tid < 512) {
    int b = tid >> 6, d = (tid >> 2) & 15, kg = tid & 3;
    const float* src = &X0T[(b * 16 + d) * X0TS];
    uint32_t* drow = (uint32_t*)&XKT[(b * 16 + d) * XKTS + kg * 16];
#pragma unroll
    for (int i2 = 0; i2 < 8; i2++) {
      int k0 = kg * 16 + i2 * 2;
      uint32_t lo = (k0 < 39)     ? (uint32_t)f2bf(src[k0])     : 0u;
      uint32_t hi = (k0 + 1 < 39) ? (uint32_t)f2bf(src[k0 + 1]) : 0u;
      drow[i2] = lo | (hi << 16);
    }
  }
  __syncthreads();   // XKT build visible for Bf loads

  // per-wave global W base (u16 units) — bg-pair waves share addresses (L1)
  const uint16_t* wlane = wt + st * 1024 + (size_t)lane * 8;

  // seed prefetch: (L0, h0)
  short8 Wc0 = *(const short8*)(wlane);
  short8 Wc1 = *(const short8*)(wlane + 512);

#pragma unroll 1
  for (int L = 0; L < 3; ++L) {
    // register-cache B-fragments (h-invariant within layer); b = bg*4 + bi
    short8 Bf0[4], Bf1[4];
#pragma unroll
    for (int bi = 0; bi < 4; ++bi) {
      const uint16_t* r = XKT + ((bg * 4 + bi) * 16 + l16) * XKTS + quad * 8;
      Bf0[bi] = *(const short8*)r;          // k 0..31 chunk
      Bf1[bi] = *(const short8*)(r + 32);   // k 32..63 chunk
    }
    const float* bp = (L == 0) ? bias0 : ((L == 1) ? bias1 : bias2);
    float bvr[4];
#pragma unroll
    for (int r = 0; r < 4; ++r) bvr[r] = bp[st * 16 + quad * 4 + r];

    floatx4 z[4] = {};
    const floatx4 zero4 = {0.f, 0.f, 0.f, 0.f};

#pragma unroll 1
    for (int h = 0; h < 40; ++h) {
      // distance-1 prefetch of next h (or next layer's h0); wave-uniform addr
      short8 Wn0, Wn1;
      {
        int Ln = L, hh = h + 1;
        if (hh >= 39) { if (L < 2) { Ln = L + 1; hh = 0; } else hh = 38; }
        const uint16_t* wl = wlane + (size_t)(Ln * F0N + hh) * WBLK;
        Wn0 = *(const short8*)wl;
        Wn1 = *(const short8*)(wl + 512);
      }

      // x0 scalars (h=39 -> 0 from pad); broadcast ds_read_b32, 2-way banks
      float xs[4];
#pragma unroll
      for (int bi = 0; bi < 4; ++bi)
        xs[bi] = X0T[((bg * 4 + bi) * 16 + l16) * X0TS + h];

#pragma unroll
      for (int bi = 0; bi < 4; ++bi) {
        floatx4 y = __builtin_amdgcn_mfma_f32_16x16x32_bf16(Wc0, Bf0[bi], zero4, 0, 0, 0);
        y = __builtin_amdgcn_mfma_f32_16x16x32_bf16(Wc1, Bf1[bi], y, 0, 0, 0);
#pragma unroll
        for (int r = 0; r < 4; ++r) z[bi][r] += xs[bi] * y[r];
      }
      Wc0 = Wn0;
      Wc1 = Wn1;
    }

    // ---- epilogue: bias+relu; xk handoff; sum_d (over l16) -> out ----
#pragma unroll
    for (int bi = 0; bi < 4; ++bi) {
      const int b = bg * 4 + bi;
#pragma unroll
      for (int r = 0; r < 4; ++r) {
        float t = fmaxf(z[bi][r] + bvr[r], 0.f);
        if (L < 2 && st < 4)               // xk = relu(z)[:, :64]; k = s < 64
          XKT[(b * 16 + l16) * XKTS + st * 16 + quad * 4 + r] = f2bf(t);
        float s4 = t;                       // reduce over d = l16 (bits 0..3)
        s4 += __shfl_xor(s4, 1);
        s4 += __shfl_xor(s4, 2);
        s4 += __shfl_xor(s4, 4);
        s4 += __shfl_xor(s4, 8);
        if (l16 == 0) {
          int s = st * 16 + quad * 4 + r;
          // concat: L0 s64:128 -> 0:64 ; L1 s64:128 -> 64:128 ; L2 s -> 128:256
          if (L == 2)       out[(size_t)(bbase + b) * 256 + 128 + s] = s4;
          else if (s >= 64) out[(size_t)(bbase + b) * 256 + L * 64 + (s - 64)] = s4;
        }
      }
    }
    if (L < 2) __syncthreads();   // handoff writes visible before next-layer Bf loads
  }
}

extern "C" void kernel_launch(void* const* d_in, const int* in_sizes, int n_in,
                              void* d_out, int out_size, void* d_ws, size_t ws_size,
                              hipStream_t stream) {
  (void)in_sizes; (void)n_in; (void)out_size; (void)ws_size;
  const float* x  = (const float*)d_in[0];
  const float* w0 = (const float*)d_in[1];
  const float* b0 = (const float*)d_in[2];
  const float* w1 = (const float*)d_in[3];
  const float* b1 = (const float*)d_in[4];
  const float* w2 = (const float*)d_in[5];
  const float* b2 = (const float*)d_in[6];
  uint16_t* wt    = (uint16_t*)d_ws;   // 117 * 8192 * 2 = 1,916,928 B

  cin_prepass<<<NHB2, 256, 0, stream>>>(w0, w1, w2, wt);
  cin_main<<<256, 1024, 0, stream>>>(x, b0, b1, b2, wt, (float*)d_out);
}